// Round 5
// baseline (129.858 us; speedup 1.0000x reference)
//
#include <hip/hip_runtime.h>
#include <hip/hip_bf16.h>
#include <math.h>

// Problem constants: B=1024 batch, L=256 latent, H=512 hidden, T=16 types,
// N=128 nodes (num_nodes input is a fixed scalar = 128).
#define BB 1024
#define LL 256
#define HH 512
#define TT 16
#define NN 128

#define NODE_F4 (BB * NN * TT / 4)   // 524288 float4
#define EDGE_F4 (BB * NN * NN / 4)   // 4194304 float4

typedef short bf16x8 __attribute__((ext_vector_type(8)));   // 8 bf16 = 4 VGPRs
typedef short s16x4  __attribute__((ext_vector_type(4)));   // 4 bf16 = 8 B
typedef float f32x4  __attribute__((ext_vector_type(4)));   // MFMA C/D

static __device__ __forceinline__ short bfbits(float f) {
    __hip_bfloat16 h = __float2bfloat16(f);
    return *reinterpret_cast<short*>(&h);
}

// ---------------------------------------------------------------------------
// K_PREP — weight transposes to bf16 B^T layouts, 416 blocks by range:
//   [0,128)   WzT[n][k]   = bf16(Wz[k][n])                   (512x256)
//   [128,384) WsumT[n][k] = bf16(We1[k][n] + We1[k+512][n])  (512x512, fold)
//   [384,416) WnT[t][k]   = bf16(Wn[k][t])                   (16x512)
__device__ __forceinline__ void transpose_tile(const float* __restrict__ in,
                                               __hip_bfloat16* __restrict__ out,
                                               int k0, int n0, int Kdim, bool fold,
                                               __hip_bfloat16 (*tile)[34]) {
    const int tx = threadIdx.x & 31;
    const int ty = threadIdx.x >> 5;          // 0..7
    #pragma unroll
    for (int r = ty; r < 32; r += 8) {
        float v = in[(k0 + r) * HH + n0 + tx];        // both weights have 512 cols
        if (fold) v += in[(k0 + r + HH) * HH + n0 + tx];
        tile[r][tx] = __float2bfloat16(v);
    }
    __syncthreads();
    #pragma unroll
    for (int r = ty; r < 32; r += 8) {
        out[(n0 + r) * Kdim + k0 + tx] = tile[tx][r];
    }
}

__global__ __launch_bounds__(256) void k_prep(const float* __restrict__ Wz,
                                              const float* __restrict__ We1,
                                              const float* __restrict__ Wn,
                                              __hip_bfloat16* __restrict__ WzT,
                                              __hip_bfloat16* __restrict__ WsumT,
                                              __hip_bfloat16* __restrict__ WnT) {
    __shared__ __hip_bfloat16 tile[32][34];
    const int bid = blockIdx.x;
    if (bid < 128) {                          // 16 n-tiles x 8 k-tiles
        const int t = bid;
        transpose_tile(Wz, WzT, (t >> 4) * 32, (t & 15) * 32, LL, false, tile);
    } else if (bid < 384) {                   // 16 n-tiles x 16 k-tiles
        const int t = bid - 128;
        transpose_tile(We1, WsumT, (t >> 4) * 32, (t & 15) * 32, HH, true, tile);
    } else {
        const int u = (bid - 384) * 256 + threadIdx.x;   // 0..8191
        WnT[u] = __float2bfloat16(Wn[(u & 511) * TT + (u >> 9)]);
    }
}

// ---------------------------------------------------------------------------
// K_FUSED — one block per 16-row batch strip (64 blocks x 1024 threads):
//   phase 0: z-strip fp32 -> bf16 LDS
//   phase 1: h = relu(z @ Wz + bz)      -> LDS only (never global)
//   phase 2: e1 = relu(h @ Wsum + be1); row-dot with We2 -> in-block reduce
//   phase 3: node16 tile = h @ WnT^T (K split across the 16 waves)
//   epilogue: p[b] = sigmoid(dot + be2); node16 + bn -> global (64KB total)
// MFMA layouts (m89/m92/m120-verified): A[m=lane&15][k=quad*8+j] contiguous;
// B-frag identical from B^T; C/D col=lane&15, row=quad*4+reg.
__global__ __launch_bounds__(1024) void k_fused(const float* __restrict__ z,
                                                const __hip_bfloat16* __restrict__ WzT,
                                                const __hip_bfloat16* __restrict__ WsumT,
                                                const __hip_bfloat16* __restrict__ WnT,
                                                const float* __restrict__ bz,
                                                const float* __restrict__ be1,
                                                const float* __restrict__ We2,
                                                const float* __restrict__ be2,
                                                const float* __restrict__ bn,
                                                float* __restrict__ node16,
                                                float* __restrict__ p) {
    constexpr int ZP = 264;                   // z_s row stride (shorts), 264*2%128!=0
    constexpr int HP = 520;                   // h_s row stride (shorts)
    __shared__ short z_s[16 * ZP];            // ~8.3 KB
    __shared__ short h_s[16 * HP];            // ~16.3 KB
    __shared__ float red[16][16];             // p-dot partials [wave][row]
    __shared__ float nacc[16][256];           // node partials  [wave][row*16+t]

    const int tid  = threadIdx.x;
    const int w    = tid >> 6;                // wave 0..15
    const int lane = tid & 63;
    const int l16  = lane & 15;
    const int quad = lane >> 4;
    const int row0 = blockIdx.x * 16;         // strip batch rows

    // phase 0: z strip (16 x 256 fp32 = 1024 float4) -> bf16 LDS
    {
        float4 v = ((const float4*)(z + row0 * LL))[tid];
        const int r = tid >> 6;               // 64 f4 per row
        const int c = (tid & 63) * 4;
        s16x4 o;
        o.x = bfbits(v.x); o.y = bfbits(v.y); o.z = bfbits(v.z); o.w = bfbits(v.w);
        *(s16x4*)(z_s + r * ZP + c) = o;
    }
    __syncthreads();

    const int nt0 = 2 * w, nt1 = 2 * w + 1;   // each wave owns 2 column tiles
    const int c0 = nt0 * 16 + l16, c1 = nt1 * 16 + l16;

    // phase 1: G1 (K=256, 8 kt, 2 tiles -> 16 MFMAs/wave)
    f32x4 a0 = {0.f, 0.f, 0.f, 0.f}, a1 = {0.f, 0.f, 0.f, 0.f};
    {
        const short* Az = z_s + l16 * ZP + quad * 8;
        const short* B0 = (const short*)WzT + c0 * LL + quad * 8;
        const short* B1 = (const short*)WzT + c1 * LL + quad * 8;
        #pragma unroll 4
        for (int kt = 0; kt < LL / 32; ++kt) {
            bf16x8 a  = *(const bf16x8*)(Az + kt * 32);
            bf16x8 b0 = *(const bf16x8*)(B0 + kt * 32);
            bf16x8 b1 = *(const bf16x8*)(B1 + kt * 32);
            a0 = __builtin_amdgcn_mfma_f32_16x16x32_bf16(a, b0, a0, 0, 0, 0);
            a1 = __builtin_amdgcn_mfma_f32_16x16x32_bf16(a, b1, a1, 0, 0, 0);
        }
    }
    {
        const float bb0 = bz[c0], bb1 = bz[c1];
        #pragma unroll
        for (int r = 0; r < 4; ++r) {
            h_s[(quad * 4 + r) * HP + c0] = bfbits(fmaxf(a0[r] + bb0, 0.f));
            h_s[(quad * 4 + r) * HP + c1] = bfbits(fmaxf(a1[r] + bb1, 0.f));
        }
    }
    __syncthreads();

    // phase 2: G2 (K=512, 16 kt, 2 tiles -> 32 MFMAs/wave), e1 stays in regs
    a0 = (f32x4){0.f, 0.f, 0.f, 0.f}; a1 = (f32x4){0.f, 0.f, 0.f, 0.f};
    {
        const short* Ah = h_s + l16 * HP + quad * 8;
        const short* B0 = (const short*)WsumT + c0 * HH + quad * 8;
        const short* B1 = (const short*)WsumT + c1 * HH + quad * 8;
        #pragma unroll 4
        for (int kt = 0; kt < HH / 32; ++kt) {
            bf16x8 a  = *(const bf16x8*)(Ah + kt * 32);
            bf16x8 b0 = *(const bf16x8*)(B0 + kt * 32);
            bf16x8 b1 = *(const bf16x8*)(B1 + kt * 32);
            a0 = __builtin_amdgcn_mfma_f32_16x16x32_bf16(a, b0, a0, 0, 0, 0);
            a1 = __builtin_amdgcn_mfma_f32_16x16x32_bf16(a, b1, a1, 0, 0, 0);
        }
    }
    {
        const float e0 = be1[c0], e1b = be1[c1];
        const float w0 = We2[c0], w1 = We2[c1];
        float s[4];
        #pragma unroll
        for (int r = 0; r < 4; ++r)
            s[r] = fmaxf(a0[r] + e0, 0.f) * w0 + fmaxf(a1[r] + e1b, 0.f) * w1;
        #pragma unroll
        for (int off = 1; off < 16; off <<= 1) {
            #pragma unroll
            for (int r = 0; r < 4; ++r) s[r] += __shfl_xor(s[r], off);
        }
        if (l16 == 0) {
            #pragma unroll
            for (int r = 0; r < 4; ++r) red[w][quad * 4 + r] = s[r];
        }
    }

    // phase 3: node16 partial — wave w handles k-slice kt = w (1 MFMA)
    {
        bf16x8 a = *(const bf16x8*)(h_s + l16 * HP + w * 32 + quad * 8);
        bf16x8 b = *(const bf16x8*)((const short*)WnT + l16 * HH + w * 32 + quad * 8);
        f32x4 na = {0.f, 0.f, 0.f, 0.f};
        na = __builtin_amdgcn_mfma_f32_16x16x32_bf16(a, b, na, 0, 0, 0);
        #pragma unroll
        for (int r = 0; r < 4; ++r) nacc[w][(quad * 4 + r) * 16 + l16] = na[r];
    }
    __syncthreads();

    // epilogue: finalize p (16 rows) and node16 (16x16)
    if (tid < 16) {
        float s = be2[0];
        #pragma unroll
        for (int ww = 0; ww < 16; ++ww) s += red[ww][tid];
        p[row0 + tid] = 1.f / (1.f + expf(-s));
    }
    if (tid < 256) {
        float s = bn[tid & 15];
        #pragma unroll
        for (int ww = 0; ww < 16; ++ww) s += nacc[ww][tid];
        node16[(row0 + (tid >> 4)) * TT + (tid & 15)] = s;
    }
}

// ---------------------------------------------------------------------------
// K_WRITE: the 72 MiB output write (the roofline term, ~13 us).
// out = [node_logits 1024x128x16][edge_probs 1024x128x128] fp32.
__global__ __launch_bounds__(256) void k_write(const float* __restrict__ node16,
                                               const float* __restrict__ p,
                                               float4* __restrict__ out) {
    const int q = blockIdx.x * 256 + threadIdx.x;
    if (q < NODE_F4) {
        const int b  = q >> 9;           // N*T/4 = 512 f4 per batch row
        const int t4 = q & 3;
        out[q] = ((const float4*)(node16 + b * TT))[t4];
    } else {
        const int e  = q - NODE_F4;
        const int b  = e >> 12;          // N*N/4 = 4096 f4 per batch row
        const int i  = (e >> 5) & 127;
        const int j0 = (e & 31) * 4;
        const float pv = p[b];
        float4 v;
        v.x = (j0 + 0 < i) ? pv : 0.f;
        v.y = (j0 + 1 < i) ? pv : 0.f;
        v.z = (j0 + 2 < i) ? pv : 0.f;
        v.w = (j0 + 3 < i) ? pv : 0.f;
        out[q] = v;
    }
}

// ---------------------------------------------------------------------------
extern "C" void kernel_launch(void* const* d_in, const int* in_sizes, int n_in,
                              void* d_out, int out_size, void* d_ws, size_t ws_size,
                              hipStream_t stream) {
    const float* z    = (const float*)d_in[0];
    // d_in[1] = num_nodes (int scalar) — fixed at 128, hard-coded as NN.
    const float* Wz   = (const float*)d_in[2];
    const float* bz   = (const float*)d_in[3];
    const float* Wn   = (const float*)d_in[4];
    const float* bn   = (const float*)d_in[5];
    const float* We1  = (const float*)d_in[6];
    const float* be1  = (const float*)d_in[7];
    const float* We2  = (const float*)d_in[8];
    const float* be2  = (const float*)d_in[9];
    float* out = (float*)d_out;

    // Workspace (bytes, 256B-aligned):
    char* base = (char*)d_ws;
    __hip_bfloat16* WzT    = (__hip_bfloat16*)(base);                 // 256 KB [512][256]
    __hip_bfloat16* WsumT  = (__hip_bfloat16*)(base +  256 * 1024);   // 512 KB [512][512]
    __hip_bfloat16* WnT    = (__hip_bfloat16*)(base +  768 * 1024);   //  16 KB [16][512]
    float*          node16 = (float*)(base + 784 * 1024);             //  64 KB [1024][16]
    float*          p      = (float*)(base + 848 * 1024);             //   4 KB

    // 1) weight transposes (bf16 B^T layouts)
    k_prep<<<416, 256, 0, stream>>>(Wz, We1, Wn, WzT, WsumT, WnT);

    // 2) fused z->h->{p, node16} (h never leaves LDS)
    k_fused<<<64, 1024, 0, stream>>>(z, WzT, WsumT, WnT, bz, be1, We2, be2, bn,
                                     node16, p);

    // 3) 72 MiB output write
    k_write<<<(NODE_F4 + EDGE_F4) / 256, 256, 0, stream>>>(node16, p, (float4*)out);

    (void)in_sizes; (void)n_in; (void)out_size; (void)ws_size;
}